// Round 5
// baseline (556.395 us; speedup 1.0000x reference)
//
#include <hip/hip_runtime.h>
#include <hip/hip_cooperative_groups.h>

namespace cg = cooperative_groups;

#define D 32
#define EPS 1e-5f
#define TPB 256
#define NB 256          // blocks for fallback streaming passes
#define GRID 512        // cooperative grid (2 blocks/CU guaranteed resident)

// ======================================================================
// MEGA: whole pipeline in one cooperative kernel.
// Phases: P0 zero -> P1 hist -> P2 partials+relscan -> P3 scan partials
//         -> P4 dst_base -> P5 scatter -> P6 compute+stats -> P7 reduce
// ======================================================================
__global__ void __launch_bounds__(TPB)
mega_kernel(const float* __restrict__ h, const float* __restrict__ W,
            const float* __restrict__ gamma, const float* __restrict__ beta,
            const int* __restrict__ src, const int* __restrict__ dst,
            const int* __restrict__ etype,
            float* __restrict__ out, int* __restrict__ ws,
            int E, int N, int R)
{
    cg::grid_group grid = cg::this_grid();
    const int tid  = threadIdx.x;
    const int bid  = blockIdx.x;
    const int nblk = gridDim.x;
    const int gsz  = nblk * TPB;
    const int gid  = bid * TPB + tid;

    const int T   = R + (E + TPB - 1) / TPB;
    const int NBS = (N + TPB - 1) / TPB;

    // ---- workspace layout (must mirror host) ----
    float* stat_sum = (float*)ws;
    float* stat_sq  = (float*)ws + D;
    int* relHist    = ws + 2 * D;
    int* cnt        = relHist + R;
    const int zwords = 2 * D + R + N;
    int* cursor_rel = ws + zwords;
    int* n_tasks_g  = cursor_rel + R;
    int* rel_start  = n_tasks_g + 1;
    int* task_rel   = rel_start + R + 1;
    int* task_start = task_rel + T;
    int* blockpart  = task_start + T;
    int* dst_base   = blockpart + NBS;
    int* cursor_dst = dst_base + N + 1;
    int* ssrc       = cursor_dst + N;
    int* tpos       = ssrc + E;
    size_t mo = (size_t)(tpos - ws) + (size_t)E;
    mo = (mo + 3) & ~(size_t)3;
    float* msg = (float*)(ws + mo);

    __shared__ float s_tile[TPB * 33];
    __shared__ int   s_i0[TPB];
    __shared__ float s_aux[2 * TPB];
    int* s_i1 = (int*)s_aux;     // 512 ints, aliased when s_aux unused

    // ---- P0: zero stats + relHist + cnt ----
    for (int i = gid; i < zwords; i += gsz) ws[i] = 0;
    grid.sync();

    // ---- P1: relation histogram (LDS-agg) + dst counts ----
    for (int r = tid; r < R; r += TPB) s_i0[r] = 0;
    __syncthreads();
    for (int e = gid; e < E; e += gsz) {
        atomicAdd(&s_i0[etype[e]], 1);
        atomicAdd(&cnt[dst[e]], 1);
    }
    __syncthreads();
    for (int r = tid; r < R; r += TPB)
        if (s_i0[r]) atomicAdd(&relHist[r], s_i0[r]);
    grid.sync();

    // ---- P2: dst per-chunk partial sums; block0 also rel scan + tasks ----
    for (int j = bid; j < NBS; j += nblk) {
        const int i = j * TPB + tid;
        s_i0[tid] = (i < N) ? cnt[i] : 0;
        __syncthreads();
        for (int off = TPB / 2; off > 0; off >>= 1) {
            if (tid < off) s_i0[tid] += s_i0[tid + off];
            __syncthreads();
        }
        if (tid == 0) blockpart[j] = s_i0[0];
        __syncthreads();
    }
    if (bid == 0) {
        int* s_rel = s_i1;            // R
        int* s_st  = s_i1 + R;        // R+1
        int* s_tb  = s_i1 + 2 * R + 1;// R   (3R+1 <= 512 ints, R <= 128 guarded)
        if (tid < R) s_rel[tid] = relHist[tid];
        __syncthreads();
        if (tid == 0) {
            int acc = 0, tb = 0;
            for (int rr = 0; rr < R; ++rr) {
                s_st[rr] = acc; s_tb[rr] = tb;
                acc += s_rel[rr];
                tb  += (s_rel[rr] + TPB - 1) / TPB;
            }
            s_st[R] = acc;
            *n_tasks_g = tb;
        }
        __syncthreads();
        if (tid < R) {
            const int st = s_st[tid];
            rel_start[tid]  = st;
            cursor_rel[tid] = st;
            const int nb = (s_rel[tid] + TPB - 1) / TPB;
            const int tb = s_tb[tid];
            for (int b = 0; b < nb; ++b) {
                task_rel[tb + b]   = tid;
                task_start[tb + b] = st + b * TPB;
            }
        }
        if (tid == 0) rel_start[R] = s_st[R];
    }
    grid.sync();

    // ---- P3: block0 exclusive-scans the NBS partials (NBS <= TPB) ----
    if (bid == 0) {
        s_i0[tid] = (tid < NBS) ? blockpart[tid] : 0;
        __syncthreads();
        if (tid == 0) {
            int acc = 0;
            for (int j = 0; j < NBS; ++j) { const int v = s_i0[j]; s_i0[j] = acc; acc += v; }
        }
        __syncthreads();
        if (tid < NBS) blockpart[tid] = s_i0[tid];
    }
    grid.sync();

    // ---- P4: dst_base / cursor_dst via per-chunk inclusive scan ----
    for (int j = bid; j < NBS; j += nblk) {
        const int i = j * TPB + tid;
        const int c = (i < N) ? cnt[i] : 0;
        s_i0[tid] = c;
        __syncthreads();
        for (int off = 1; off < TPB; off <<= 1) {
            const int v = (tid >= off) ? s_i0[tid - off] : 0;
            __syncthreads();
            s_i0[tid] += v;
            __syncthreads();
        }
        if (i < N) {
            const int b = blockpart[j] + s_i0[tid] - c;   // exclusive prefix
            dst_base[i]   = b;
            cursor_dst[i] = b;
        }
        __syncthreads();
    }
    if (gid == 0) dst_base[N] = E;
    grid.sync();

    // ---- P5: scatter into rel-sorted order + dst-order slot ----
    {
        const int chunkE = (E + nblk - 1) / nblk;
        const int lo = bid * chunkE, hi = min(E, lo + chunkE);
        for (int r = tid; r < R; r += TPB) s_i0[r] = 0;
        __syncthreads();
        for (int e = lo + tid; e < hi; e += TPB)
            atomicAdd(&s_i0[etype[e]], 1);
        __syncthreads();
        for (int r = tid; r < R; r += TPB)
            s_i1[r] = s_i0[r] ? atomicAdd(&cursor_rel[r], s_i0[r]) : 0;
        __syncthreads();
        for (int e = lo + tid; e < hi; e += TPB) {
            const int p = atomicAdd(&s_i1[etype[e]], 1);    // LDS cursor
            ssrc[p] = src[e];
            tpos[p] = atomicAdd(&cursor_dst[dst[e]], 1);    // dst-order slot
        }
    }
    grid.sync();

    // ---- P6: per-task GEMV + relu + verified stats + store to msg ----
    const int nt = *n_tasks_g;
    for (int task = bid; task < nt; task += nblk) {
        const int r      = task_rel[task];
        const int start  = task_start[task];
        const int relEnd = rel_start[r + 1];
        const int nE     = min(TPB, relEnd - start);

        if (tid < nE) s_i0[tid] = tpos[start + tid];

        const float* Wr = W + (size_t)__builtin_amdgcn_readfirstlane(r) * (D * D);
        if (tid < nE) {
            const int s = ssrc[start + tid];
            float acc[D];
#pragma unroll
            for (int o = 0; o < D; ++o) acc[o] = 0.f;
            const float4* hp = (const float4*)(h + (size_t)s * D);
#pragma unroll
            for (int c4 = 0; c4 < D / 4; ++c4) {
                const float4 hv = hp[c4];
                const float hx[4] = {hv.x, hv.y, hv.z, hv.w};
#pragma unroll
                for (int jj = 0; jj < 4; ++jj) {
                    const float hd = hx[jj];
                    const int d = c4 * 4 + jj;
#pragma unroll
                    for (int o = 0; o < D; ++o)
                        acc[o] = fmaf(hd, Wr[d * D + o], acc[o]);
                }
            }
#pragma unroll
            for (int o = 0; o < D; ++o)
                s_tile[tid * 33 + o] = fmaxf(acc[o], 0.f);
        }
        __syncthreads();   // covers s_tile and s_i0

        float ps = 0.f, pq = 0.f;
        for (int i = tid; i < nE * D; i += TPB) {
            const int row = i >> 5, o = i & 31;   // o == tid&31: fixed dim
            const float v = s_tile[row * 33 + o];
            msg[(size_t)s_i0[row] * D + o] = v;   // coalesced 128B per row
            ps += v; pq += v * v;
        }
        s_aux[tid]       = ps;
        s_aux[TPB + tid] = pq;
        __syncthreads();
        if (tid < D) {
            float ss = 0.f, sq = 0.f;
#pragma unroll
            for (int c = 0; c < TPB / D; ++c) {
                ss += s_aux[c * D + tid];
                sq += s_aux[TPB + c * D + tid];
            }
            atomicAdd(&stat_sum[tid], ss);
            atomicAdd(&stat_sq[tid], sq);
        }
        __syncthreads();   // protect s_tile/s_i0/s_aux for next task
    }
    grid.sync();

    // ---- P7: contiguous segment reduce + BN affine + mean ----
    {
        float* s_sc = s_aux;
        float* s_sh = s_aux + D;
        if (tid < D) {
            const float invE = 1.0f / (float)E;
            const float mu  = stat_sum[tid] * invE;
            const float var = fmaxf(stat_sq[tid] * invE - mu * mu, 0.f);
            const float is  = rsqrtf(var + EPS);
            const float sc  = gamma[tid] * is;
            s_sc[tid] = sc;
            s_sh[tid] = fmaf(-mu, sc, beta[tid]);
        }
        __syncthreads();
        const int o = tid & (D - 1);
        for (int node = bid * (TPB / D) + (tid >> 5); node < N;
             node += nblk * (TPB / D)) {
            const int b0 = dst_base[node], b1 = dst_base[node + 1];
            float v = 0.f;
            for (int q = b0; q < b1; ++q)
                v += msg[(size_t)q * D + o];
            const float c = (float)(b1 - b0);
            out[(size_t)node * D + o] = fmaf(v, s_sc[o], s_sh[o] * c) / fmaxf(c, 1.0f);
        }
    }
}

// ======================================================================
// FALLBACK A (R4 path, verified passing): separate dispatches
// ======================================================================

__global__ void hist3_kernel(const int* __restrict__ etype, const int* __restrict__ dst,
                             int E, int R, int chunk,
                             int* __restrict__ blockHistT, int* __restrict__ cnt)
{
    __shared__ int lh[1024];
    for (int i = threadIdx.x; i < R; i += TPB) lh[i] = 0;
    __syncthreads();
    const int lo = blockIdx.x * chunk, hi = min(E, lo + chunk);
    for (int e = lo + threadIdx.x; e < hi; e += TPB) {
        atomicAdd(&lh[etype[e]], 1);
        atomicAdd(&cnt[dst[e]], 1);
    }
    __syncthreads();
    for (int r = threadIdx.x; r < R; r += TPB)
        blockHistT[r * NB + blockIdx.x] = lh[r];
}

__global__ __launch_bounds__(1024)
void scan3_kernel(int* __restrict__ blockHistT, int R, int N, int E,
                  int* __restrict__ rel_start,
                  int* __restrict__ task_rel, int* __restrict__ task_start,
                  int* __restrict__ n_tasks,
                  const int* __restrict__ cnt,
                  int* __restrict__ dst_base, int* __restrict__ cursor_dst)
{
    const int t = threadIdx.x;
    __shared__ int tot[1024];
    __shared__ int s_start[1025];
    __shared__ int s_tbase[1024];
    __shared__ int sb[1024];

    if (t < R) {
        int acc = 0;
        int* p = blockHistT + t * NB;
        for (int b = 0; b < NB; ++b) { int v = p[b]; p[b] = acc; acc += v; }
        tot[t] = acc;
    }
    __syncthreads();
    if (t == 0) {
        int acc = 0, tb = 0;
        for (int rr = 0; rr < R; ++rr) {
            s_start[rr] = acc; s_tbase[rr] = tb;
            acc += tot[rr];
            tb  += (tot[rr] + TPB - 1) / TPB;
        }
        s_start[R] = acc;
        rel_start[R] = acc;
        *n_tasks = tb;
    }
    __syncthreads();
    if (t < R) {
        const int st = s_start[t];
        rel_start[t] = st;
        const int nb = (tot[t] + TPB - 1) / TPB;
        const int tb = s_tbase[t];
        for (int b = 0; b < nb; ++b) {
            task_rel[tb + b]   = t;
            task_start[tb + b] = st + b * TPB;
        }
    }

    const int chunk = (N + 1023) >> 10;
    const int lo = t * chunk, hi = min(N, lo + chunk);
    int part = 0;
    for (int i = lo; i < hi; ++i) part += cnt[i];
    sb[t] = part;
    __syncthreads();
    for (int off = 1; off < 1024; off <<= 1) {
        const int v = (t >= off) ? sb[t - off] : 0;
        __syncthreads();
        sb[t] += v;
        __syncthreads();
    }
    int base = sb[t] - part;
    for (int i = lo; i < hi; ++i) {
        dst_base[i]   = base;
        cursor_dst[i] = base;
        base += cnt[i];
    }
    if (t == 0) dst_base[N] = E;
}

__global__ void scatter3_kernel(const int* __restrict__ src, const int* __restrict__ dst,
                                const int* __restrict__ etype, int E, int R, int chunk,
                                const int* __restrict__ blockHistT,
                                const int* __restrict__ rel_start,
                                int* __restrict__ cursor_dst,
                                int* __restrict__ ssrc, int* __restrict__ perm)
{
    __shared__ int cur[1024];
    for (int r = threadIdx.x; r < R; r += TPB)
        cur[r] = rel_start[r] + blockHistT[r * NB + blockIdx.x];
    __syncthreads();
    const int lo = blockIdx.x * chunk, hi = min(E, lo + chunk);
    for (int e = lo + threadIdx.x; e < hi; e += TPB) {
        const int p = atomicAdd(&cur[etype[e]], 1);
        ssrc[p] = src[e];
        const int q = atomicAdd(&cursor_dst[dst[e]], 1);
        perm[q] = p;
    }
}

__global__ __launch_bounds__(TPB)
void rgcn_main3(const float* __restrict__ h, const float* __restrict__ W,
                const int* __restrict__ rel_start,
                const int* __restrict__ task_rel, const int* __restrict__ task_start,
                const int* __restrict__ n_tasks_p,
                const int* __restrict__ ssrc,
                float* __restrict__ msg,
                float* __restrict__ stat_sum, float* __restrict__ stat_sq)
{
    __shared__ float s_tile[TPB * 33];
    __shared__ int   s_src[TPB];
    __shared__ float s_aux[2 * TPB];

    const int task = blockIdx.x;
    if (task >= *n_tasks_p) return;
    const int r      = task_rel[task];
    const int start  = task_start[task];
    const int relEnd = rel_start[r + 1];
    const int nE     = min(TPB, relEnd - start);
    const int tid    = threadIdx.x;

    if (tid < nE) s_src[tid] = ssrc[start + tid];
    __syncthreads();

    for (int i = tid; i < nE * 8; i += TPB) {
        const int row = i >> 3, seg = i & 7;
        const float4 v = *(const float4*)(h + (size_t)s_src[row] * D + seg * 4);
        float* p = &s_tile[row * 33 + seg * 4];
        p[0] = v.x; p[1] = v.y; p[2] = v.z; p[3] = v.w;
    }
    __syncthreads();

    const float* Wr = W + (size_t)__builtin_amdgcn_readfirstlane(r) * (D * D);

    float acc[D];
#pragma unroll
    for (int o = 0; o < D; ++o) acc[o] = 0.f;

    if (tid < nE) {
#pragma unroll 4
        for (int d = 0; d < D; ++d) {
            const float hd = s_tile[tid * 33 + d];
#pragma unroll
            for (int o = 0; o < D; ++o)
                acc[o] = fmaf(hd, Wr[d * D + o], acc[o]);
        }
#pragma unroll
        for (int o = 0; o < D; ++o) acc[o] = fmaxf(acc[o], 0.f);
    }
    __syncthreads();

    if (tid < nE) {
#pragma unroll
        for (int o = 0; o < D; ++o) s_tile[tid * 33 + o] = acc[o];
    }
    __syncthreads();

    float* mbase = msg + (size_t)start * D;
    float ps = 0.f, pq = 0.f;
    for (int i = tid; i < nE * D; i += TPB) {
        const int row = i >> 5, o = i & 31;
        const float v = s_tile[row * 33 + o];
        mbase[i] = v;
        ps += v; pq += v * v;
    }
    s_aux[tid]       = ps;
    s_aux[TPB + tid] = pq;
    __syncthreads();
    if (tid < D) {
        float ss = 0.f, sq = 0.f;
#pragma unroll
        for (int c = 0; c < TPB / D; ++c) {
            ss += s_aux[c * D + tid];
            sq += s_aux[TPB + c * D + tid];
        }
        atomicAdd(&stat_sum[tid], ss);
        atomicAdd(&stat_sq[tid], sq);
    }
}

__global__ __launch_bounds__(TPB)
void reduce3_kernel(const float* __restrict__ msg, const int* __restrict__ perm,
                    const int* __restrict__ dst_base,
                    const float* __restrict__ stat_sum, const float* __restrict__ stat_sq,
                    const float* __restrict__ gamma, const float* __restrict__ beta,
                    float invE, int N, float* __restrict__ out)
{
    __shared__ float s_sc[D], s_sh[D];
    const int tid = threadIdx.x;
    if (tid < D) {
        const float mu  = stat_sum[tid] * invE;
        const float var = fmaxf(stat_sq[tid] * invE - mu * mu, 0.f);
        const float is  = rsqrtf(var + EPS);
        const float sc  = gamma[tid] * is;
        s_sc[tid] = sc;
        s_sh[tid] = fmaf(-mu, sc, beta[tid]);
    }
    __syncthreads();
    const int o    = tid & (D - 1);
    const int node = blockIdx.x * (TPB / D) + (tid >> 5);
    if (node >= N) return;
    const int b0 = dst_base[node], b1 = dst_base[node + 1];
    float v = 0.f;
    for (int q = b0; q < b1; ++q) {
        const int pe = perm[q];
        v += msg[(size_t)pe * D + o];
    }
    const float c = (float)(b1 - b0);
    out[(size_t)node * D + o] = fmaf(v, s_sc[o], s_sh[o] * c) / fmaxf(c, 1.0f);
}

// ======================================================================
// FALLBACK B (original old path) — unchanged, verified
// ======================================================================

__global__ void hist2_kernel(const int* __restrict__ etype, int E, int R, int chunk,
                             int* __restrict__ blockHistT)
{
    __shared__ int lh[1024];
    for (int i = threadIdx.x; i < R; i += TPB) lh[i] = 0;
    __syncthreads();
    const int lo = blockIdx.x * chunk, hi = min(E, lo + chunk);
    for (int e = lo + threadIdx.x; e < hi; e += TPB)
        atomicAdd(&lh[etype[e]], 1);
    __syncthreads();
    for (int r = threadIdx.x; r < R; r += TPB)
        blockHistT[r * NB + blockIdx.x] = lh[r];
}

__global__ void scan2_kernel(int* __restrict__ blockHistT, int R,
                             int* __restrict__ rel_start,
                             int* __restrict__ task_rel, int* __restrict__ task_start,
                             int* __restrict__ n_tasks)
{
    __shared__ int tot[1024];
    __shared__ int s_start[1025];
    __shared__ int s_tbase[1024];
    const int r = threadIdx.x;
    if (r < R) {
        int acc = 0;
        int* p = blockHistT + r * NB;
        for (int b = 0; b < NB; ++b) { int v = p[b]; p[b] = acc; acc += v; }
        tot[r] = acc;
    }
    __syncthreads();
    if (threadIdx.x == 0) {
        int acc = 0, tb = 0;
        for (int rr = 0; rr < R; ++rr) {
            s_start[rr] = acc; s_tbase[rr] = tb;
            acc += tot[rr];
            tb  += (tot[rr] + TPB - 1) / TPB;
        }
        s_start[R] = acc;
        rel_start[R] = acc;
        *n_tasks = tb;
    }
    __syncthreads();
    if (r < R) {
        const int st = s_start[r];
        rel_start[r] = st;
        const int nb = (tot[r] + TPB - 1) / TPB;
        const int tb = s_tbase[r];
        for (int b = 0; b < nb; ++b) {
            task_rel[tb + b]   = r;
            task_start[tb + b] = st + b * TPB;
        }
    }
}

__global__ void scatter2_kernel(const int* __restrict__ src, const int* __restrict__ dst,
                                const int* __restrict__ etype, int E, int R, int chunk,
                                const int* __restrict__ blockHistT,
                                const int* __restrict__ rel_start,
                                int* __restrict__ ssrc, int* __restrict__ sdst)
{
    __shared__ int cur[1024];
    for (int r = threadIdx.x; r < R; r += TPB)
        cur[r] = rel_start[r] + blockHistT[r * NB + blockIdx.x];
    __syncthreads();
    const int lo = blockIdx.x * chunk, hi = min(E, lo + chunk);
    for (int e = lo + threadIdx.x; e < hi; e += TPB) {
        const int p = atomicAdd(&cur[etype[e]], 1);
        ssrc[p] = src[e];
        sdst[p] = dst[e];
    }
}

__global__ __launch_bounds__(TPB)
void rgcn_main(const float* __restrict__ h, const float* __restrict__ W,
               const int* __restrict__ rel_start,
               const int* __restrict__ task_rel, const int* __restrict__ task_start,
               const int* __restrict__ n_tasks_p,
               const int* __restrict__ ssrc, const int* __restrict__ sdst,
               float* __restrict__ out,
               float* __restrict__ stat_sum, float* __restrict__ stat_sq,
               float* __restrict__ cnt)
{
    __shared__ float s_tile[TPB * 33];
    __shared__ int   s_src[TPB];
    __shared__ int   s_dst[TPB];
    __shared__ float s_aux[2 * TPB];

    const int task = blockIdx.x;
    if (task >= *n_tasks_p) return;
    const int r      = task_rel[task];
    const int start  = task_start[task];
    const int relEnd = rel_start[r + 1];
    const int nE     = min(TPB, relEnd - start);
    const int tid    = threadIdx.x;

    if (tid < nE) {
        s_src[tid] = ssrc[start + tid];
        s_dst[tid] = sdst[start + tid];
    }
    __syncthreads();

    for (int i = tid; i < nE * 8; i += TPB) {
        const int row = i >> 3, seg = i & 7;
        const float4 v = *(const float4*)(h + (size_t)s_src[row] * D + seg * 4);
        float* p = &s_tile[row * 33 + seg * 4];
        p[0] = v.x; p[1] = v.y; p[2] = v.z; p[3] = v.w;
    }
    __syncthreads();

    const float* Wr = W + (size_t)__builtin_amdgcn_readfirstlane(r) * (D * D);

    float acc[D];
#pragma unroll
    for (int o = 0; o < D; ++o) acc[o] = 0.f;

    if (tid < nE) {
#pragma unroll 4
        for (int d = 0; d < D; ++d) {
            const float hd = s_tile[tid * 33 + d];
#pragma unroll
            for (int o = 0; o < D; ++o)
                acc[o] = fmaf(hd, Wr[d * D + o], acc[o]);
        }
#pragma unroll
        for (int o = 0; o < D; ++o) acc[o] = fmaxf(acc[o], 0.f);
        atomicAdd(&cnt[s_dst[tid]], 1.0f);
    }
    __syncthreads();

    if (tid < nE) {
#pragma unroll
        for (int o = 0; o < D; ++o) s_tile[tid * 33 + o] = acc[o];
    }
    __syncthreads();

    float ps = 0.f, pq = 0.f;
    for (int i = tid; i < nE * D; i += TPB) {
        const int row = i >> 5, o = i & 31;
        const float v = s_tile[row * 33 + o];
        atomicAdd(&out[(size_t)s_dst[row] * D + o], v);
        ps += v; pq += v * v;
    }
    s_aux[tid]       = ps;
    s_aux[TPB + tid] = pq;
    __syncthreads();
    if (tid < D) {
        float ss = 0.f, sq = 0.f;
#pragma unroll
        for (int c = 0; c < TPB / D; ++c) {
            ss += s_aux[c * D + tid];
            sq += s_aux[TPB + c * D + tid];
        }
        atomicAdd(&stat_sum[tid], ss);
        atomicAdd(&stat_sq[tid], sq);
    }
}

__global__ void finalize_kernel(float* __restrict__ out, const float* __restrict__ cnt,
                                const float* __restrict__ stat_sum,
                                const float* __restrict__ stat_sq,
                                const float* __restrict__ gamma,
                                const float* __restrict__ beta,
                                float invE, int total)
{
    const int i = blockIdx.x * TPB + threadIdx.x;
    if (i >= total) return;
    const int o    = i & 31;
    const int node = i >> 5;
    const float mu  = stat_sum[o] * invE;
    const float var = fmaxf(stat_sq[o] * invE - mu * mu, 0.f);
    const float is  = rsqrtf(var + EPS);
    const float sc  = gamma[o] * is;
    const float sh  = fmaf(-mu, sc, beta[o]);
    const float c   = cnt[node];
    out[i] = fmaf(out[i], sc, sh * c) / fmaxf(c, 1.0f);
}

// ======================================================================
extern "C" void kernel_launch(void* const* d_in, const int* in_sizes, int n_in,
                              void* d_out, int out_size, void* d_ws, size_t ws_size,
                              hipStream_t stream)
{
    const float* h     = (const float*)d_in[0];
    const float* W     = (const float*)d_in[1];
    const float* gamma = (const float*)d_in[2];
    const float* beta  = (const float*)d_in[3];
    const int*   src   = (const int*)d_in[4];
    const int*   dst   = (const int*)d_in[5];
    const int*   etype = (const int*)d_in[6];
    float* out = (float*)d_out;

    const int E = in_sizes[4];
    const int N = in_sizes[0] / D;
    const int R = in_sizes[1] / (D * D);
    const int T = R + (E + TPB - 1) / TPB;
    const int NBS = (N + TPB - 1) / TPB;
    const int chunk = (E + NB - 1) / NB;

    // ---------------- mega workspace size (mirrors kernel) ---------------
    {
        const size_t zw = 2 * D + R + (size_t)N;
        size_t off = zw + R + 1 + (R + 1) + (size_t)T + T + NBS
                     + (N + 1) + (size_t)N + (size_t)E + (size_t)E;
        const size_t o_msg = (off + 3) & ~(size_t)3;
        const size_t total = o_msg + (size_t)E * D;
        if (R <= 128 && NBS <= TPB && ws_size >= total * 4) {
            int* wsp = (int*)d_ws;
            int Ee = E, Nn = N, Rr = R;
            void* args[] = {(void*)&h, (void*)&W, (void*)&gamma, (void*)&beta,
                            (void*)&src, (void*)&dst, (void*)&etype,
                            (void*)&out, (void*)&wsp,
                            (void*)&Ee, (void*)&Nn, (void*)&Rr};
            const hipError_t err = hipLaunchCooperativeKernel(
                (const void*)mega_kernel, dim3(GRID), dim3(TPB), args, 0, stream);
            if (err == hipSuccess) return;
        }
    }

    // ---------------- FALLBACK A: R4 path (verified) ----------------------
    {
        const size_t o_stat_sum   = 0;
        const size_t o_stat_sq    = o_stat_sum + D;
        const size_t o_cnt        = o_stat_sq + D;
        const size_t zwords       = o_cnt + (size_t)N;
        const size_t o_rel_start  = zwords;
        const size_t o_n_tasks    = o_rel_start + R + 1;
        const size_t o_task_rel   = o_n_tasks + 1;
        const size_t o_task_start = o_task_rel + T;
        const size_t o_blockHistT = o_task_start + T;
        const size_t o_dst_base   = o_blockHistT + (size_t)R * NB;
        const size_t o_cursor_dst = o_dst_base + N + 1;
        const size_t o_ssrc       = o_cursor_dst + N;
        const size_t o_perm       = o_ssrc + (size_t)E;
        const size_t o_msg        = (o_perm + (size_t)E + 3) & ~(size_t)3;
        const size_t total_words  = o_msg + (size_t)E * D;

        if (ws_size >= total_words * 4) {
            float* stat_sum   = (float*)d_ws + o_stat_sum;
            float* stat_sq    = (float*)d_ws + o_stat_sq;
            int*   cnt        = (int*)d_ws + o_cnt;
            int*   rel_start  = (int*)d_ws + o_rel_start;
            int*   n_tasks    = (int*)d_ws + o_n_tasks;
            int*   task_rel   = (int*)d_ws + o_task_rel;
            int*   task_start = (int*)d_ws + o_task_start;
            int*   blockHistT = (int*)d_ws + o_blockHistT;
            int*   dst_base   = (int*)d_ws + o_dst_base;
            int*   cursor_dst = (int*)d_ws + o_cursor_dst;
            int*   ssrc       = (int*)d_ws + o_ssrc;
            int*   perm       = (int*)d_ws + o_perm;
            float* msg        = (float*)d_ws + o_msg;

            hipMemsetAsync(d_ws, 0, zwords * 4, stream);

            hist3_kernel<<<NB, TPB, 0, stream>>>(etype, dst, E, R, chunk,
                                                 blockHistT, cnt);
            scan3_kernel<<<1, 1024, 0, stream>>>(blockHistT, R, N, E,
                                                 rel_start, task_rel, task_start,
                                                 n_tasks, cnt, dst_base, cursor_dst);
            scatter3_kernel<<<NB, TPB, 0, stream>>>(src, dst, etype, E, R, chunk,
                                                    blockHistT, rel_start,
                                                    cursor_dst, ssrc, perm);
            rgcn_main3<<<T, TPB, 0, stream>>>(h, W, rel_start, task_rel, task_start,
                                              n_tasks, ssrc, msg, stat_sum, stat_sq);
            reduce3_kernel<<<(N + TPB / D - 1) / (TPB / D), TPB, 0, stream>>>(
                msg, perm, dst_base, stat_sum, stat_sq, gamma, beta,
                1.0f / (float)E, N, out);
            return;
        }
    }

    // ---------------- FALLBACK B: old path --------------------------------
    float* stat_sum  = (float*)d_ws;
    float* stat_sq   = stat_sum + D;
    float* cntf      = stat_sq + D;
    int*   rel_start = (int*)(cntf + N);
    int*   n_tasks   = rel_start + R + 1;
    int*   task_rel  = n_tasks + 1;
    int*   task_start= task_rel + T;
    int*   blockHistT= task_start + T;
    int*   ssrc      = blockHistT + R * NB;
    int*   sdst      = ssrc + E;

    hipMemsetAsync(d_ws, 0, sizeof(float) * (size_t)(2 * D + N), stream);
    hipMemsetAsync(d_out, 0, sizeof(float) * (size_t)out_size, stream);

    hist2_kernel<<<NB, TPB, 0, stream>>>(etype, E, R, chunk, blockHistT);
    scan2_kernel<<<1, TPB, 0, stream>>>(blockHistT, R, rel_start,
                                        task_rel, task_start, n_tasks);
    scatter2_kernel<<<NB, TPB, 0, stream>>>(src, dst, etype, E, R, chunk,
                                            blockHistT, rel_start, ssrc, sdst);
    rgcn_main<<<T, TPB, 0, stream>>>(h, W, rel_start, task_rel, task_start,
                                     n_tasks, ssrc, sdst, out,
                                     stat_sum, stat_sq, cntf);
    finalize_kernel<<<(N * D + TPB - 1) / TPB, TPB, 0, stream>>>(
        out, cntf, stat_sum, stat_sq, gamma, beta, 1.0f / (float)E, N * D);
}

// Round 6
// 199.254 us; speedup vs baseline: 2.7924x; 2.7924x over previous
//
#include <hip/hip_runtime.h>

#define D 32
#define EPS 1e-5f
#define TPB 256
#define NB 256          // blocks for streaming passes

// ======================================================================
// PATH v6 (all verified pieces):
//   memset(~81KB) -> h1_hist -> s2_scan -> c3_scatter -> rgcn_main3 -> reduce3
//  - h1_hist  : R2 k1_hist (LDS-agg relHist + dst cnt)           [verified R2]
//  - s2_scan  : R2 k2_scan (serial rel scan + tasks + dst scan)  [verified R2]
//  - c3_scatter: R2 k3 reservation + R4 perm[q]=p write          [both verified]
//  - rgcn_main3: R4 (coalesced msg stores, no output atomics)    [verified R4]
//  - reduce3  : R4 (perm-gather contiguous dst segments + BN)    [verified R4]
// ======================================================================

// ---- H1: relation histogram (LDS-aggregated) + per-dst counts --------
__global__ void h1_hist(const int* __restrict__ etype, const int* __restrict__ dst,
                        int E, int R,
                        int* __restrict__ relHist, int* __restrict__ cnt)
{
    __shared__ int lh[1024];
    for (int i = threadIdx.x; i < R; i += TPB) lh[i] = 0;
    __syncthreads();
    for (int e = blockIdx.x * TPB + threadIdx.x; e < E; e += gridDim.x * TPB) {
        atomicAdd(&lh[etype[e]], 1);
        atomicAdd(&cnt[dst[e]], 1);
    }
    __syncthreads();
    for (int r = threadIdx.x; r < R; r += TPB)
        if (lh[r]) atomicAdd(&relHist[r], lh[r]);
}

// ---- S2: rel scan + task list + dst exclusive scan (single block) ----
__global__ __launch_bounds__(1024)
void s2_scan(const int* __restrict__ relHist, int R, int E, int N,
             int* __restrict__ rel_start, int* __restrict__ cursor_rel,
             int* __restrict__ task_rel, int* __restrict__ task_start,
             int* __restrict__ n_tasks,
             const int* __restrict__ cnt,
             int* __restrict__ dst_base, int* __restrict__ cursor_dst)
{
    const int t = threadIdx.x;
    __shared__ int sb[1024];
    __shared__ int s_start[1025];
    __shared__ int s_tbase[1024];

    // relation exclusive scan + task bases (R tiny, serial on t0)
    if (t == 0) {
        int acc = 0, tb = 0;
        for (int r = 0; r < R; ++r) {
            s_start[r] = acc; s_tbase[r] = tb;
            const int v = relHist[r];
            acc += v;
            tb  += (v + TPB - 1) / TPB;
        }
        s_start[R] = acc;
        *n_tasks = tb;
    }
    __syncthreads();
    if (t < R) {
        const int st = s_start[t];
        rel_start[t]  = st;
        cursor_rel[t] = st;
        const int tot = s_start[t + 1] - st;
        const int nb  = (tot + TPB - 1) / TPB;
        const int tb  = s_tbase[t];
        for (int b = 0; b < nb; ++b) {
            task_rel[tb + b]   = t;
            task_start[tb + b] = st + b * TPB;
        }
    }
    if (t == 0) rel_start[R] = s_start[R];

    // dst exclusive scan over N bins (chunk per thread + Hillis-Steele)
    const int chunk = (N + 1023) >> 10;
    const int lo = t * chunk, hi = min(N, lo + chunk);
    int part = 0;
    for (int i = lo; i < hi; ++i) part += cnt[i];
    sb[t] = part;
    __syncthreads();
    for (int off = 1; off < 1024; off <<= 1) {
        const int v = (t >= off) ? sb[t - off] : 0;
        __syncthreads();
        sb[t] += v;
        __syncthreads();
    }
    int base = sb[t] - part;            // exclusive prefix of this chunk
    for (int i = lo; i < hi; ++i) {
        dst_base[i]   = base;
        cursor_dst[i] = base;
        base += cnt[i];
    }
    if (t == 0) dst_base[N] = E;
}

// ---- C3: scatter into rel-sorted order + dst-order perm --------------
__global__ void c3_scatter(const int* __restrict__ src, const int* __restrict__ dst,
                           const int* __restrict__ etype, int E, int R,
                           int* __restrict__ cursor_rel, int* __restrict__ cursor_dst,
                           int* __restrict__ ssrc, int* __restrict__ perm)
{
    __shared__ int lh[1024];
    __shared__ int lcur[1024];
    for (int r = threadIdx.x; r < R; r += TPB) lh[r] = 0;
    __syncthreads();
    const int chunk = (E + gridDim.x - 1) / gridDim.x;
    const int lo = blockIdx.x * chunk, hi = min(E, lo + chunk);
    for (int e = lo + threadIdx.x; e < hi; e += TPB)
        atomicAdd(&lh[etype[e]], 1);
    __syncthreads();
    for (int r = threadIdx.x; r < R; r += TPB)
        lcur[r] = lh[r] ? atomicAdd(&cursor_rel[r], lh[r]) : 0;
    __syncthreads();
    for (int e = lo + threadIdx.x; e < hi; e += TPB) {
        const int p = atomicAdd(&lcur[etype[e]], 1);       // LDS cursor
        ssrc[p] = src[e];
        const int q = atomicAdd(&cursor_dst[dst[e]], 1);   // dst-order slot
        perm[q] = p;                                       // dst-order -> rel-order
    }
}

// ---- MAIN: rel-task GEMV + relu + stats + coalesced msg stores -------
__global__ __launch_bounds__(TPB)
void rgcn_main3(const float* __restrict__ h, const float* __restrict__ W,
                const int* __restrict__ rel_start,
                const int* __restrict__ task_rel, const int* __restrict__ task_start,
                const int* __restrict__ n_tasks_p,
                const int* __restrict__ ssrc,
                float* __restrict__ msg,
                float* __restrict__ stat_sum, float* __restrict__ stat_sq)
{
    __shared__ float s_tile[TPB * 33];
    __shared__ int   s_src[TPB];
    __shared__ float s_aux[2 * TPB];

    const int task = blockIdx.x;
    if (task >= *n_tasks_p) return;
    const int r      = task_rel[task];
    const int start  = task_start[task];
    const int relEnd = rel_start[r + 1];
    const int nE     = min(TPB, relEnd - start);
    const int tid    = threadIdx.x;

    if (tid < nE) s_src[tid] = ssrc[start + tid];
    __syncthreads();

    for (int i = tid; i < nE * 8; i += TPB) {
        const int row = i >> 3, seg = i & 7;
        const float4 v = *(const float4*)(h + (size_t)s_src[row] * D + seg * 4);
        float* p = &s_tile[row * 33 + seg * 4];
        p[0] = v.x; p[1] = v.y; p[2] = v.z; p[3] = v.w;
    }
    __syncthreads();

    const float* Wr = W + (size_t)__builtin_amdgcn_readfirstlane(r) * (D * D);

    float acc[D];
#pragma unroll
    for (int o = 0; o < D; ++o) acc[o] = 0.f;

    if (tid < nE) {
#pragma unroll 4
        for (int d = 0; d < D; ++d) {
            const float hd = s_tile[tid * 33 + d];
#pragma unroll
            for (int o = 0; o < D; ++o)
                acc[o] = fmaf(hd, Wr[d * D + o], acc[o]);
        }
#pragma unroll
        for (int o = 0; o < D; ++o) acc[o] = fmaxf(acc[o], 0.f);
    }
    __syncthreads();

    if (tid < nE) {
#pragma unroll
        for (int o = 0; o < D; ++o) s_tile[tid * 33 + o] = acc[o];
    }
    __syncthreads();

    // coalesced plain stores: i = row*32 + o is exactly the msg offset
    float* mbase = msg + (size_t)start * D;
    float ps = 0.f, pq = 0.f;
    for (int i = tid; i < nE * D; i += TPB) {
        const int row = i >> 5, o = i & 31;   // o == tid&31: fixed dim per thread
        const float v = s_tile[row * 33 + o];
        mbase[i] = v;
        ps += v; pq += v * v;
    }
    s_aux[tid]       = ps;
    s_aux[TPB + tid] = pq;
    __syncthreads();
    if (tid < D) {
        float ss = 0.f, sq = 0.f;
#pragma unroll
        for (int c = 0; c < TPB / D; ++c) {
            ss += s_aux[c * D + tid];
            sq += s_aux[TPB + c * D + tid];
        }
        atomicAdd(&stat_sum[tid], ss);
        atomicAdd(&stat_sq[tid], sq);
    }
}

// ---- REDUCE: dst-segment gather via perm + BN affine + mean ----------
__global__ __launch_bounds__(TPB)
void reduce3_kernel(const float* __restrict__ msg, const int* __restrict__ perm,
                    const int* __restrict__ dst_base,
                    const float* __restrict__ stat_sum, const float* __restrict__ stat_sq,
                    const float* __restrict__ gamma, const float* __restrict__ beta,
                    float invE, int N, float* __restrict__ out)
{
    __shared__ float s_sc[D], s_sh[D];
    const int tid = threadIdx.x;
    if (tid < D) {
        const float mu  = stat_sum[tid] * invE;
        const float var = fmaxf(stat_sq[tid] * invE - mu * mu, 0.f);
        const float is  = rsqrtf(var + EPS);
        const float sc  = gamma[tid] * is;
        s_sc[tid] = sc;
        s_sh[tid] = fmaf(-mu, sc, beta[tid]);
    }
    __syncthreads();
    const int o    = tid & (D - 1);
    const int node = blockIdx.x * (TPB / D) + (tid >> 5);
    if (node >= N) return;
    const int b0 = dst_base[node], b1 = dst_base[node + 1];
    float v = 0.f;
    for (int q = b0; q < b1; ++q) {
        const int pe = perm[q];                    // broadcast within 32-lane group
        v += msg[(size_t)pe * D + o];              // one 128B line per edge
    }
    const float c = (float)(b1 - b0);
    out[(size_t)node * D + o] = fmaf(v, s_sc[o], s_sh[o] * c) / fmaxf(c, 1.0f);
}

// ======================================================================
// FALLBACK (original old path, verified R0) — used when ws too small
// ======================================================================

__global__ void hist2_kernel(const int* __restrict__ etype, int E, int R, int chunk,
                             int* __restrict__ blockHistT)
{
    __shared__ int lh[1024];
    for (int i = threadIdx.x; i < R; i += TPB) lh[i] = 0;
    __syncthreads();
    const int lo = blockIdx.x * chunk, hi = min(E, lo + chunk);
    for (int e = lo + threadIdx.x; e < hi; e += TPB)
        atomicAdd(&lh[etype[e]], 1);
    __syncthreads();
    for (int r = threadIdx.x; r < R; r += TPB)
        blockHistT[r * NB + blockIdx.x] = lh[r];
}

__global__ void scan2_kernel(int* __restrict__ blockHistT, int R,
                             int* __restrict__ rel_start,
                             int* __restrict__ task_rel, int* __restrict__ task_start,
                             int* __restrict__ n_tasks)
{
    __shared__ int tot[1024];
    __shared__ int s_start[1025];
    __shared__ int s_tbase[1024];
    const int r = threadIdx.x;
    if (r < R) {
        int acc = 0;
        int* p = blockHistT + r * NB;
        for (int b = 0; b < NB; ++b) { int v = p[b]; p[b] = acc; acc += v; }
        tot[r] = acc;
    }
    __syncthreads();
    if (threadIdx.x == 0) {
        int acc = 0, tb = 0;
        for (int rr = 0; rr < R; ++rr) {
            s_start[rr] = acc; s_tbase[rr] = tb;
            acc += tot[rr];
            tb  += (tot[rr] + TPB - 1) / TPB;
        }
        s_start[R] = acc;
        rel_start[R] = acc;
        *n_tasks = tb;
    }
    __syncthreads();
    if (r < R) {
        const int st = s_start[r];
        rel_start[r] = st;
        const int nb = (tot[r] + TPB - 1) / TPB;
        const int tb = s_tbase[r];
        for (int b = 0; b < nb; ++b) {
            task_rel[tb + b]   = r;
            task_start[tb + b] = st + b * TPB;
        }
    }
}

__global__ void scatter2_kernel(const int* __restrict__ src, const int* __restrict__ dst,
                                const int* __restrict__ etype, int E, int R, int chunk,
                                const int* __restrict__ blockHistT,
                                const int* __restrict__ rel_start,
                                int* __restrict__ ssrc, int* __restrict__ sdst)
{
    __shared__ int cur[1024];
    for (int r = threadIdx.x; r < R; r += TPB)
        cur[r] = rel_start[r] + blockHistT[r * NB + blockIdx.x];
    __syncthreads();
    const int lo = blockIdx.x * chunk, hi = min(E, lo + chunk);
    for (int e = lo + threadIdx.x; e < hi; e += TPB) {
        const int p = atomicAdd(&cur[etype[e]], 1);
        ssrc[p] = src[e];
        sdst[p] = dst[e];
    }
}

__global__ __launch_bounds__(TPB)
void rgcn_main(const float* __restrict__ h, const float* __restrict__ W,
               const int* __restrict__ rel_start,
               const int* __restrict__ task_rel, const int* __restrict__ task_start,
               const int* __restrict__ n_tasks_p,
               const int* __restrict__ ssrc, const int* __restrict__ sdst,
               float* __restrict__ out,
               float* __restrict__ stat_sum, float* __restrict__ stat_sq,
               float* __restrict__ cnt)
{
    __shared__ float s_tile[TPB * 33];
    __shared__ int   s_src[TPB];
    __shared__ int   s_dst[TPB];
    __shared__ float s_aux[2 * TPB];

    const int task = blockIdx.x;
    if (task >= *n_tasks_p) return;
    const int r      = task_rel[task];
    const int start  = task_start[task];
    const int relEnd = rel_start[r + 1];
    const int nE     = min(TPB, relEnd - start);
    const int tid    = threadIdx.x;

    if (tid < nE) {
        s_src[tid] = ssrc[start + tid];
        s_dst[tid] = sdst[start + tid];
    }
    __syncthreads();

    for (int i = tid; i < nE * 8; i += TPB) {
        const int row = i >> 3, seg = i & 7;
        const float4 v = *(const float4*)(h + (size_t)s_src[row] * D + seg * 4);
        float* p = &s_tile[row * 33 + seg * 4];
        p[0] = v.x; p[1] = v.y; p[2] = v.z; p[3] = v.w;
    }
    __syncthreads();

    const float* Wr = W + (size_t)__builtin_amdgcn_readfirstlane(r) * (D * D);

    float acc[D];
#pragma unroll
    for (int o = 0; o < D; ++o) acc[o] = 0.f;

    if (tid < nE) {
#pragma unroll 4
        for (int d = 0; d < D; ++d) {
            const float hd = s_tile[tid * 33 + d];
#pragma unroll
            for (int o = 0; o < D; ++o)
                acc[o] = fmaf(hd, Wr[d * D + o], acc[o]);
        }
#pragma unroll
        for (int o = 0; o < D; ++o) acc[o] = fmaxf(acc[o], 0.f);
        atomicAdd(&cnt[s_dst[tid]], 1.0f);
    }
    __syncthreads();

    if (tid < nE) {
#pragma unroll
        for (int o = 0; o < D; ++o) s_tile[tid * 33 + o] = acc[o];
    }
    __syncthreads();

    float ps = 0.f, pq = 0.f;
    for (int i = tid; i < nE * D; i += TPB) {
        const int row = i >> 5, o = i & 31;
        const float v = s_tile[row * 33 + o];
        atomicAdd(&out[(size_t)s_dst[row] * D + o], v);
        ps += v; pq += v * v;
    }
    s_aux[tid]       = ps;
    s_aux[TPB + tid] = pq;
    __syncthreads();
    if (tid < D) {
        float ss = 0.f, sq = 0.f;
#pragma unroll
        for (int c = 0; c < TPB / D; ++c) {
            ss += s_aux[c * D + tid];
            sq += s_aux[TPB + c * D + tid];
        }
        atomicAdd(&stat_sum[tid], ss);
        atomicAdd(&stat_sq[tid], sq);
    }
}

__global__ void finalize_kernel(float* __restrict__ out, const float* __restrict__ cnt,
                                const float* __restrict__ stat_sum,
                                const float* __restrict__ stat_sq,
                                const float* __restrict__ gamma,
                                const float* __restrict__ beta,
                                float invE, int total)
{
    const int i = blockIdx.x * TPB + threadIdx.x;
    if (i >= total) return;
    const int o    = i & 31;
    const int node = i >> 5;
    const float mu  = stat_sum[o] * invE;
    const float var = fmaxf(stat_sq[o] * invE - mu * mu, 0.f);
    const float is  = rsqrtf(var + EPS);
    const float sc  = gamma[o] * is;
    const float sh  = fmaf(-mu, sc, beta[o]);
    const float c   = cnt[node];
    out[i] = fmaf(out[i], sc, sh * c) / fmaxf(c, 1.0f);
}

// ======================================================================
extern "C" void kernel_launch(void* const* d_in, const int* in_sizes, int n_in,
                              void* d_out, int out_size, void* d_ws, size_t ws_size,
                              hipStream_t stream)
{
    const float* h     = (const float*)d_in[0];
    const float* W     = (const float*)d_in[1];
    const float* gamma = (const float*)d_in[2];
    const float* beta  = (const float*)d_in[3];
    const int*   src   = (const int*)d_in[4];
    const int*   dst   = (const int*)d_in[5];
    const int*   etype = (const int*)d_in[6];
    float* out = (float*)d_out;

    const int E = in_sizes[4];
    const int N = in_sizes[0] / D;
    const int R = in_sizes[1] / (D * D);
    const int T = R + (E + TPB - 1) / TPB;        // max task count
    const int chunk = (E + NB - 1) / NB;

    // ---------------- v6 workspace layout (dword offsets) ----------------
    const size_t o_stat_sum   = 0;
    const size_t o_stat_sq    = o_stat_sum + D;
    const size_t o_relHist    = o_stat_sq + D;
    const size_t o_cursor_rel = o_relHist + R;
    const size_t o_n_tasks    = o_cursor_rel + R;
    const size_t o_cnt        = o_n_tasks + 1;
    const size_t zwords       = o_cnt + (size_t)N;          // zeroed prefix
    const size_t o_rel_start  = zwords;
    const size_t o_task_rel   = o_rel_start + R + 1;
    const size_t o_task_start = o_task_rel + T;
    const size_t o_dst_base   = o_task_start + T;
    const size_t o_cursor_dst = o_dst_base + N + 1;
    const size_t o_ssrc       = o_cursor_dst + N;
    const size_t o_perm       = o_ssrc + (size_t)E;
    const size_t o_msg        = (o_perm + (size_t)E + 3) & ~(size_t)3;   // 16B align
    const size_t total_words  = o_msg + (size_t)E * D;

    if (ws_size >= total_words * 4) {
        // ------------------------- PATH v6 -------------------------------
        float* stat_sum   = (float*)d_ws + o_stat_sum;
        float* stat_sq    = (float*)d_ws + o_stat_sq;
        int*   relHist    = (int*)d_ws + o_relHist;
        int*   cursor_rel = (int*)d_ws + o_cursor_rel;
        int*   n_tasks    = (int*)d_ws + o_n_tasks;
        int*   cnt        = (int*)d_ws + o_cnt;
        int*   rel_start  = (int*)d_ws + o_rel_start;
        int*   task_rel   = (int*)d_ws + o_task_rel;
        int*   task_start = (int*)d_ws + o_task_start;
        int*   dst_base   = (int*)d_ws + o_dst_base;
        int*   cursor_dst = (int*)d_ws + o_cursor_dst;
        int*   ssrc       = (int*)d_ws + o_ssrc;
        int*   perm       = (int*)d_ws + o_perm;
        float* msg        = (float*)d_ws + o_msg;

        hipMemsetAsync(d_ws, 0, zwords * 4, stream);

        h1_hist<<<NB, TPB, 0, stream>>>(etype, dst, E, R, relHist, cnt);
        s2_scan<<<1, 1024, 0, stream>>>(relHist, R, E, N,
                                        rel_start, cursor_rel,
                                        task_rel, task_start, n_tasks,
                                        cnt, dst_base, cursor_dst);
        c3_scatter<<<NB, TPB, 0, stream>>>(src, dst, etype, E, R,
                                           cursor_rel, cursor_dst, ssrc, perm);
        rgcn_main3<<<T, TPB, 0, stream>>>(h, W, rel_start, task_rel, task_start,
                                          n_tasks, ssrc, msg, stat_sum, stat_sq);
        reduce3_kernel<<<(N + TPB / D - 1) / (TPB / D), TPB, 0, stream>>>(
            msg, perm, dst_base, stat_sum, stat_sq, gamma, beta,
            1.0f / (float)E, N, out);
        return;
    }

    // --------------------------- OLD PATH --------------------------------
    float* stat_sum  = (float*)d_ws;
    float* stat_sq   = stat_sum + D;
    float* cntf      = stat_sq + D;
    int*   rel_start = (int*)(cntf + N);
    int*   n_tasks   = rel_start + R + 1;
    int*   task_rel  = n_tasks + 1;
    int*   task_start= task_rel + T;
    int*   blockHistT= task_start + T;
    int*   ssrc      = blockHistT + R * NB;
    int*   sdst      = ssrc + E;

    hipMemsetAsync(d_ws, 0, sizeof(float) * (size_t)(2 * D + N), stream);
    hipMemsetAsync(d_out, 0, sizeof(float) * (size_t)out_size, stream);

    hist2_kernel<<<NB, TPB, 0, stream>>>(etype, E, R, chunk, blockHistT);
    scan2_kernel<<<1, TPB, 0, stream>>>(blockHistT, R, rel_start,
                                        task_rel, task_start, n_tasks);
    scatter2_kernel<<<NB, TPB, 0, stream>>>(src, dst, etype, E, R, chunk,
                                            blockHistT, rel_start, ssrc, sdst);
    rgcn_main<<<T, TPB, 0, stream>>>(h, W, rel_start, task_rel, task_start,
                                     n_tasks, ssrc, sdst, out,
                                     stat_sum, stat_sq, cntf);
    finalize_kernel<<<(N * D + TPB - 1) / TPB, TPB, 0, stream>>>(
        out, cntf, stat_sum, stat_sq, gamma, beta, 1.0f / (float)E, N * D);
}

// Round 7
// 183.138 us; speedup vs baseline: 3.0381x; 1.0880x over previous
//
#include <hip/hip_runtime.h>

#define D 32
#define EPS 1e-5f
#define TPB 256
#define NB 256          // sort-pass blocks; MUST equal TPB for scanA
#define NSLOT 64        // stat accumulation slots (contention 782/64 ~ 12)

// ======================================================================
// PATH v7:
//   memset -> hist3 -> scanA -> scanB -> scatter3 -> main3 -> reduce3
//  - hist3   : R4-verified per-block rel hist (transposed) + dst cnt
//  - scanA   : NEW parallel per-row exclusive scan of blockHistT (R blocks)
//  - scanB   : rel/task scan via 1024-wide HS + verified dst HS scan
//  - scatter3: R4-verified (LDS cursors from blockHistT, perm[q]=p)
//  - main3   : R4-verified GEMV/relu/msg-store; stats -> 64-slot two-level
//  - reduce3 : R4-verified perm-gather; folds 64 stat slots
// ======================================================================

// ---- S1: per-block rel histogram (transposed) + global dst counts ----
__global__ void hist3_kernel(const int* __restrict__ etype, const int* __restrict__ dst,
                             int E, int R, int chunk,
                             int* __restrict__ blockHistT,   // [R][NB]
                             int* __restrict__ cnt)          // [N]
{
    __shared__ int lh[1024];
    for (int i = threadIdx.x; i < R; i += TPB) lh[i] = 0;
    __syncthreads();
    const int lo = blockIdx.x * chunk, hi = min(E, lo + chunk);
    for (int e = lo + threadIdx.x; e < hi; e += TPB) {
        atomicAdd(&lh[etype[e]], 1);
        atomicAdd(&cnt[dst[e]], 1);
    }
    __syncthreads();
    for (int r = threadIdx.x; r < R; r += TPB)
        blockHistT[r * NB + blockIdx.x] = lh[r];
}

// ---- S2a: parallel exclusive scan of each blockHistT row (grid = R) --
__global__ __launch_bounds__(TPB)
void scanA_kernel(int* __restrict__ blockHistT, int* __restrict__ relTot)
{
    const int r = blockIdx.x;
    const int t = threadIdx.x;
    __shared__ int s[TPB];
    const int v = blockHistT[r * NB + t];
    s[t] = v;
    __syncthreads();
    for (int off = 1; off < TPB; off <<= 1) {
        const int u = (t >= off) ? s[t - off] : 0;
        __syncthreads();
        s[t] += u;
        __syncthreads();
    }
    blockHistT[r * NB + t] = s[t] - v;          // exclusive prefix
    if (t == TPB - 1) relTot[r] = s[t];         // row total
}

// ---- S2b: rel scan + task list (HS over R) + dst exclusive scan ------
__global__ __launch_bounds__(1024)
void scanB_kernel(const int* __restrict__ relTot, int R, int E, int N,
                  int* __restrict__ rel_start,
                  int* __restrict__ task_rel, int* __restrict__ task_start,
                  int* __restrict__ n_tasks,
                  const int* __restrict__ cnt,
                  int* __restrict__ dst_base, int* __restrict__ cursor_dst)
{
    const int t = threadIdx.x;
    __shared__ int sa[1024];   // rel totals scan
    __shared__ int sc[1024];   // task-count scan
    __shared__ int sb[1024];   // dst chunk partial scan

    // --- relation scan + task bases (both via HS, R <= 1024) ---
    const int tot = (t < R) ? relTot[t] : 0;
    const int nb  = (tot + TPB - 1) / TPB;
    sa[t] = tot; sc[t] = nb;
    __syncthreads();
    for (int off = 1; off < 1024; off <<= 1) {
        const int va = (t >= off) ? sa[t - off] : 0;
        const int vc = (t >= off) ? sc[t - off] : 0;
        __syncthreads();
        sa[t] += va; sc[t] += vc;
        __syncthreads();
    }
    if (t < R) {
        const int st = sa[t] - tot;     // exclusive
        const int tb = sc[t] - nb;
        rel_start[t] = st;
        for (int b = 0; b < nb; ++b) {
            task_rel[tb + b]   = t;
            task_start[tb + b] = st + b * TPB;
        }
    }
    if (t == R - 1) {
        rel_start[R] = sa[t];
        *n_tasks = sc[t];
    }

    // --- dst exclusive scan over N bins (verified s2 pattern) ---
    const int chunk = (N + 1023) >> 10;
    const int lo = t * chunk, hi = min(N, lo + chunk);
    int part = 0;
    for (int i = lo; i < hi; ++i) part += cnt[i];
    sb[t] = part;
    __syncthreads();
    for (int off = 1; off < 1024; off <<= 1) {
        const int v = (t >= off) ? sb[t - off] : 0;
        __syncthreads();
        sb[t] += v;
        __syncthreads();
    }
    int base = sb[t] - part;            // exclusive prefix of this chunk
    for (int i = lo; i < hi; ++i) {
        dst_base[i]   = base;
        cursor_dst[i] = base;
        base += cnt[i];
    }
    if (t == 0) dst_base[N] = E;
}

// ---- S3: scatter into rel-sorted order + dst-order perm (R4) ---------
__global__ void scatter3_kernel(const int* __restrict__ src, const int* __restrict__ dst,
                                const int* __restrict__ etype, int E, int R, int chunk,
                                const int* __restrict__ blockHistT,
                                const int* __restrict__ rel_start,
                                int* __restrict__ cursor_dst,
                                int* __restrict__ ssrc, int* __restrict__ perm)
{
    __shared__ int cur[1024];
    for (int r = threadIdx.x; r < R; r += TPB)
        cur[r] = rel_start[r] + blockHistT[r * NB + blockIdx.x];
    __syncthreads();
    const int lo = blockIdx.x * chunk, hi = min(E, lo + chunk);
    for (int e = lo + threadIdx.x; e < hi; e += TPB) {
        const int p = atomicAdd(&cur[etype[e]], 1);        // LDS cursor
        ssrc[p] = src[e];
        const int q = atomicAdd(&cursor_dst[dst[e]], 1);   // dst-order slot
        perm[q] = p;                                       // dst-order -> rel-order
    }
}

// ---- MAIN: rel-task GEMV + relu + msg stores + two-level stats -------
__global__ __launch_bounds__(TPB)
void rgcn_main3(const float* __restrict__ h, const float* __restrict__ W,
                const int* __restrict__ rel_start,
                const int* __restrict__ task_rel, const int* __restrict__ task_start,
                const int* __restrict__ n_tasks_p,
                const int* __restrict__ ssrc,
                float* __restrict__ msg,
                float* __restrict__ stat_part)   // [NSLOT][2*D]
{
    __shared__ float s_tile[TPB * 33];
    __shared__ int   s_src[TPB];
    __shared__ float s_aux[2 * TPB];

    const int task = blockIdx.x;
    if (task >= *n_tasks_p) return;
    const int r      = task_rel[task];
    const int start  = task_start[task];
    const int relEnd = rel_start[r + 1];
    const int nE     = min(TPB, relEnd - start);
    const int tid    = threadIdx.x;

    if (tid < nE) s_src[tid] = ssrc[start + tid];
    __syncthreads();

    for (int i = tid; i < nE * 8; i += TPB) {
        const int row = i >> 3, seg = i & 7;
        const float4 v = *(const float4*)(h + (size_t)s_src[row] * D + seg * 4);
        float* p = &s_tile[row * 33 + seg * 4];
        p[0] = v.x; p[1] = v.y; p[2] = v.z; p[3] = v.w;
    }
    __syncthreads();

    const float* Wr = W + (size_t)__builtin_amdgcn_readfirstlane(r) * (D * D);

    float acc[D];
#pragma unroll
    for (int o = 0; o < D; ++o) acc[o] = 0.f;

    if (tid < nE) {
#pragma unroll 4
        for (int d = 0; d < D; ++d) {
            const float hd = s_tile[tid * 33 + d];
#pragma unroll
            for (int o = 0; o < D; ++o)
                acc[o] = fmaf(hd, Wr[d * D + o], acc[o]);
        }
#pragma unroll
        for (int o = 0; o < D; ++o) acc[o] = fmaxf(acc[o], 0.f);
    }
    __syncthreads();

    if (tid < nE) {
#pragma unroll
        for (int o = 0; o < D; ++o) s_tile[tid * 33 + o] = acc[o];
    }
    __syncthreads();

    // coalesced plain stores: i = row*32 + o is exactly the msg offset
    float* mbase = msg + (size_t)start * D;
    float ps = 0.f, pq = 0.f;
    for (int i = tid; i < nE * D; i += TPB) {
        const int row = i >> 5, o = i & 31;   // o == tid&31: fixed dim per thread
        const float v = s_tile[row * 33 + o];
        mbase[i] = v;
        ps += v; pq += v * v;
    }
    s_aux[tid]       = ps;
    s_aux[TPB + tid] = pq;
    __syncthreads();
    if (tid < D) {
        float ss = 0.f, sq = 0.f;
#pragma unroll
        for (int c = 0; c < TPB / D; ++c) {
            ss += s_aux[c * D + tid];
            sq += s_aux[TPB + c * D + tid];
        }
        float* sp = stat_part + (size_t)(blockIdx.x & (NSLOT - 1)) * (2 * D);
        atomicAdd(&sp[tid],     ss);   // slot-local: ~12 collisions/address
        atomicAdd(&sp[D + tid], sq);
    }
}

// ---- REDUCE: fold stat slots + perm-gather segments + BN + mean ------
__global__ __launch_bounds__(TPB)
void reduce3_kernel(const float* __restrict__ msg, const int* __restrict__ perm,
                    const int* __restrict__ dst_base,
                    const float* __restrict__ stat_part,
                    const float* __restrict__ gamma, const float* __restrict__ beta,
                    float invE, int N, float* __restrict__ out)
{
    __shared__ float s_sc[D], s_sh[D];
    const int tid = threadIdx.x;
    if (tid < D) {
        float ss = 0.f, qq = 0.f;
#pragma unroll 4
        for (int s = 0; s < NSLOT; ++s) {
            ss += stat_part[(size_t)s * (2 * D) + tid];
            qq += stat_part[(size_t)s * (2 * D) + D + tid];
        }
        const float mu  = ss * invE;
        const float var = fmaxf(qq * invE - mu * mu, 0.f);
        const float is  = rsqrtf(var + EPS);
        const float sc  = gamma[tid] * is;
        s_sc[tid] = sc;
        s_sh[tid] = fmaf(-mu, sc, beta[tid]);
    }
    __syncthreads();
    const int o    = tid & (D - 1);
    const int node = blockIdx.x * (TPB / D) + (tid >> 5);
    if (node >= N) return;
    const int b0 = dst_base[node], b1 = dst_base[node + 1];
    float v = 0.f;
    for (int q = b0; q < b1; ++q) {
        const int pe = perm[q];                    // broadcast within 32-lane group
        v += msg[(size_t)pe * D + o];              // one 128B line per edge
    }
    const float c = (float)(b1 - b0);
    out[(size_t)node * D + o] = fmaf(v, s_sc[o], s_sh[o] * c) / fmaxf(c, 1.0f);
}

// ======================================================================
// FALLBACK (original R0 path, verified) — used when guards fail
// ======================================================================

__global__ void hist2_kernel(const int* __restrict__ etype, int E, int R, int chunk,
                             int* __restrict__ blockHistT)
{
    __shared__ int lh[1024];
    for (int i = threadIdx.x; i < R; i += TPB) lh[i] = 0;
    __syncthreads();
    const int lo = blockIdx.x * chunk, hi = min(E, lo + chunk);
    for (int e = lo + threadIdx.x; e < hi; e += TPB)
        atomicAdd(&lh[etype[e]], 1);
    __syncthreads();
    for (int r = threadIdx.x; r < R; r += TPB)
        blockHistT[r * NB + blockIdx.x] = lh[r];
}

__global__ void scan2_kernel(int* __restrict__ blockHistT, int R,
                             int* __restrict__ rel_start,
                             int* __restrict__ task_rel, int* __restrict__ task_start,
                             int* __restrict__ n_tasks)
{
    __shared__ int tot[1024];
    __shared__ int s_start[1025];
    __shared__ int s_tbase[1024];
    const int r = threadIdx.x;
    if (r < R) {
        int acc = 0;
        int* p = blockHistT + r * NB;
        for (int b = 0; b < NB; ++b) { int v = p[b]; p[b] = acc; acc += v; }
        tot[r] = acc;
    }
    __syncthreads();
    if (threadIdx.x == 0) {
        int acc = 0, tb = 0;
        for (int rr = 0; rr < R; ++rr) {
            s_start[rr] = acc; s_tbase[rr] = tb;
            acc += tot[rr];
            tb  += (tot[rr] + TPB - 1) / TPB;
        }
        s_start[R] = acc;
        rel_start[R] = acc;
        *n_tasks = tb;
    }
    __syncthreads();
    if (r < R) {
        const int st = s_start[r];
        rel_start[r] = st;
        const int nb = (tot[r] + TPB - 1) / TPB;
        const int tb = s_tbase[r];
        for (int b = 0; b < nb; ++b) {
            task_rel[tb + b]   = r;
            task_start[tb + b] = st + b * TPB;
        }
    }
}

__global__ void scatter2_kernel(const int* __restrict__ src, const int* __restrict__ dst,
                                const int* __restrict__ etype, int E, int R, int chunk,
                                const int* __restrict__ blockHistT,
                                const int* __restrict__ rel_start,
                                int* __restrict__ ssrc, int* __restrict__ sdst)
{
    __shared__ int cur[1024];
    for (int r = threadIdx.x; r < R; r += TPB)
        cur[r] = rel_start[r] + blockHistT[r * NB + blockIdx.x];
    __syncthreads();
    const int lo = blockIdx.x * chunk, hi = min(E, lo + chunk);
    for (int e = lo + threadIdx.x; e < hi; e += TPB) {
        const int p = atomicAdd(&cur[etype[e]], 1);
        ssrc[p] = src[e];
        sdst[p] = dst[e];
    }
}

__global__ __launch_bounds__(TPB)
void rgcn_main(const float* __restrict__ h, const float* __restrict__ W,
               const int* __restrict__ rel_start,
               const int* __restrict__ task_rel, const int* __restrict__ task_start,
               const int* __restrict__ n_tasks_p,
               const int* __restrict__ ssrc, const int* __restrict__ sdst,
               float* __restrict__ out,
               float* __restrict__ stat_sum, float* __restrict__ stat_sq,
               float* __restrict__ cnt)
{
    __shared__ float s_tile[TPB * 33];
    __shared__ int   s_src[TPB];
    __shared__ int   s_dst[TPB];
    __shared__ float s_aux[2 * TPB];

    const int task = blockIdx.x;
    if (task >= *n_tasks_p) return;
    const int r      = task_rel[task];
    const int start  = task_start[task];
    const int relEnd = rel_start[r + 1];
    const int nE     = min(TPB, relEnd - start);
    const int tid    = threadIdx.x;

    if (tid < nE) {
        s_src[tid] = ssrc[start + tid];
        s_dst[tid] = sdst[start + tid];
    }
    __syncthreads();

    for (int i = tid; i < nE * 8; i += TPB) {
        const int row = i >> 3, seg = i & 7;
        const float4 v = *(const float4*)(h + (size_t)s_src[row] * D + seg * 4);
        float* p = &s_tile[row * 33 + seg * 4];
        p[0] = v.x; p[1] = v.y; p[2] = v.z; p[3] = v.w;
    }
    __syncthreads();

    const float* Wr = W + (size_t)__builtin_amdgcn_readfirstlane(r) * (D * D);

    float acc[D];
#pragma unroll
    for (int o = 0; o < D; ++o) acc[o] = 0.f;

    if (tid < nE) {
#pragma unroll 4
        for (int d = 0; d < D; ++d) {
            const float hd = s_tile[tid * 33 + d];
#pragma unroll
            for (int o = 0; o < D; ++o)
                acc[o] = fmaf(hd, Wr[d * D + o], acc[o]);
        }
#pragma unroll
        for (int o = 0; o < D; ++o) acc[o] = fmaxf(acc[o], 0.f);
        atomicAdd(&cnt[s_dst[tid]], 1.0f);
    }
    __syncthreads();

    if (tid < nE) {
#pragma unroll
        for (int o = 0; o < D; ++o) s_tile[tid * 33 + o] = acc[o];
    }
    __syncthreads();

    float ps = 0.f, pq = 0.f;
    for (int i = tid; i < nE * D; i += TPB) {
        const int row = i >> 5, o = i & 31;
        const float v = s_tile[row * 33 + o];
        atomicAdd(&out[(size_t)s_dst[row] * D + o], v);
        ps += v; pq += v * v;
    }
    s_aux[tid]       = ps;
    s_aux[TPB + tid] = pq;
    __syncthreads();
    if (tid < D) {
        float ss = 0.f, sq = 0.f;
#pragma unroll
        for (int c = 0; c < TPB / D; ++c) {
            ss += s_aux[c * D + tid];
            sq += s_aux[TPB + c * D + tid];
        }
        atomicAdd(&stat_sum[tid], ss);
        atomicAdd(&stat_sq[tid], sq);
    }
}

__global__ void finalize_kernel(float* __restrict__ out, const float* __restrict__ cnt,
                                const float* __restrict__ stat_sum,
                                const float* __restrict__ stat_sq,
                                const float* __restrict__ gamma,
                                const float* __restrict__ beta,
                                float invE, int total)
{
    const int i = blockIdx.x * TPB + threadIdx.x;
    if (i >= total) return;
    const int o    = i & 31;
    const int node = i >> 5;
    const float mu  = stat_sum[o] * invE;
    const float var = fmaxf(stat_sq[o] * invE - mu * mu, 0.f);
    const float is  = rsqrtf(var + EPS);
    const float sc  = gamma[o] * is;
    const float sh  = fmaf(-mu, sc, beta[o]);
    const float c   = cnt[node];
    out[i] = fmaf(out[i], sc, sh * c) / fmaxf(c, 1.0f);
}

// ======================================================================
extern "C" void kernel_launch(void* const* d_in, const int* in_sizes, int n_in,
                              void* d_out, int out_size, void* d_ws, size_t ws_size,
                              hipStream_t stream)
{
    const float* h     = (const float*)d_in[0];
    const float* W     = (const float*)d_in[1];
    const float* gamma = (const float*)d_in[2];
    const float* beta  = (const float*)d_in[3];
    const int*   src   = (const int*)d_in[4];
    const int*   dst   = (const int*)d_in[5];
    const int*   etype = (const int*)d_in[6];
    float* out = (float*)d_out;

    const int E = in_sizes[4];
    const int N = in_sizes[0] / D;
    const int R = in_sizes[1] / (D * D);
    const int T = R + (E + TPB - 1) / TPB;        // max task count
    const int chunk = (E + NB - 1) / NB;

    // ---------------- v7 workspace layout (dword offsets) ----------------
    const size_t o_statp      = 0;                           // [NSLOT][2*D]
    const size_t o_cnt        = o_statp + (size_t)NSLOT * 2 * D;
    const size_t zwords       = o_cnt + (size_t)N;           // zeroed prefix
    const size_t o_relTot     = zwords;
    const size_t o_rel_start  = o_relTot + R;
    const size_t o_n_tasks    = o_rel_start + R + 1;
    const size_t o_task_rel   = o_n_tasks + 1;
    const size_t o_task_start = o_task_rel + T;
    const size_t o_blockHistT = o_task_start + T;
    const size_t o_dst_base   = o_blockHistT + (size_t)R * NB;
    const size_t o_cursor_dst = o_dst_base + N + 1;
    const size_t o_ssrc       = o_cursor_dst + N;
    const size_t o_perm       = o_ssrc + (size_t)E;
    const size_t o_msg        = (o_perm + (size_t)E + 3) & ~(size_t)3;  // 16B align
    const size_t total_words  = o_msg + (size_t)E * D;

    if (R >= 1 && R <= 1024 && NB == TPB && ws_size >= total_words * 4) {
        // ------------------------- PATH v7 -------------------------------
        float* stat_part  = (float*)d_ws + o_statp;
        int*   cnt        = (int*)d_ws + o_cnt;
        int*   relTot     = (int*)d_ws + o_relTot;
        int*   rel_start  = (int*)d_ws + o_rel_start;
        int*   n_tasks    = (int*)d_ws + o_n_tasks;
        int*   task_rel   = (int*)d_ws + o_task_rel;
        int*   task_start = (int*)d_ws + o_task_start;
        int*   blockHistT = (int*)d_ws + o_blockHistT;
        int*   dst_base   = (int*)d_ws + o_dst_base;
        int*   cursor_dst = (int*)d_ws + o_cursor_dst;
        int*   ssrc       = (int*)d_ws + o_ssrc;
        int*   perm       = (int*)d_ws + o_perm;
        float* msg        = (float*)d_ws + o_msg;

        hipMemsetAsync(d_ws, 0, zwords * 4, stream);

        hist3_kernel<<<NB, TPB, 0, stream>>>(etype, dst, E, R, chunk,
                                             blockHistT, cnt);
        scanA_kernel<<<R, TPB, 0, stream>>>(blockHistT, relTot);
        scanB_kernel<<<1, 1024, 0, stream>>>(relTot, R, E, N,
                                             rel_start, task_rel, task_start,
                                             n_tasks, cnt, dst_base, cursor_dst);
        scatter3_kernel<<<NB, TPB, 0, stream>>>(src, dst, etype, E, R, chunk,
                                                blockHistT, rel_start,
                                                cursor_dst, ssrc, perm);
        rgcn_main3<<<T, TPB, 0, stream>>>(h, W, rel_start, task_rel, task_start,
                                          n_tasks, ssrc, msg, stat_part);
        reduce3_kernel<<<(N + TPB / D - 1) / (TPB / D), TPB, 0, stream>>>(
            msg, perm, dst_base, stat_part, gamma, beta,
            1.0f / (float)E, N, out);
        return;
    }

    // --------------------------- OLD PATH --------------------------------
    float* stat_sum  = (float*)d_ws;
    float* stat_sq   = stat_sum + D;
    float* cntf      = stat_sq + D;
    int*   rel_start = (int*)(cntf + N);
    int*   n_tasks   = rel_start + R + 1;
    int*   task_rel  = n_tasks + 1;
    int*   task_start= task_rel + T;
    int*   blockHistT= task_start + T;
    int*   ssrc      = blockHistT + R * NB;
    int*   sdst      = ssrc + E;

    hipMemsetAsync(d_ws, 0, sizeof(float) * (size_t)(2 * D + N), stream);
    hipMemsetAsync(d_out, 0, sizeof(float) * (size_t)out_size, stream);

    hist2_kernel<<<NB, TPB, 0, stream>>>(etype, E, R, chunk, blockHistT);
    scan2_kernel<<<1, TPB, 0, stream>>>(blockHistT, R, rel_start,
                                        task_rel, task_start, n_tasks);
    scatter2_kernel<<<NB, TPB, 0, stream>>>(src, dst, etype, E, R, chunk,
                                            blockHistT, rel_start, ssrc, sdst);
    rgcn_main<<<T, TPB, 0, stream>>>(h, W, rel_start, task_rel, task_start,
                                     n_tasks, ssrc, sdst, out,
                                     stat_sum, stat_sq, cntf);
    finalize_kernel<<<(N * D + TPB - 1) / TPB, TPB, 0, stream>>>(
        out, cntf, stat_sum, stat_sq, gamma, beta, 1.0f / (float)E, N * D);
}

// Round 8
// 182.269 us; speedup vs baseline: 3.0526x; 1.0048x over previous
//
#include <hip/hip_runtime.h>

#define D 32
#define EPS 1e-5f
#define TPB 256
#define NB 256          // sort-pass blocks; MUST equal TPB
#define NSLOT 64        // stat accumulation slots

// ======================================================================
// PATH v8:
//   memset -> hist3 -> scanF -> scatter4 -> main4 -> reduceS
//  - hist3   : R7-verified per-block rel hist (transposed) + dst cnt
//  - scanF   : fused scanA+scanB (quarter-row scans + HS rel/task + HS dst)
//  - scatter4: R7-verified LDS-cursor scatter; writes tpos[p]=q (R2 form)
//  - main4   : R7-verified GEMV/relu/slot-stats; stores msg[tpos[row]] (R5 form)
//  - reduceS : R2-verified streaming segment reduce + R7 slot fold + BN
// ======================================================================

// ---- S1: per-block rel histogram (transposed) + global dst counts ----
__global__ void hist3_kernel(const int* __restrict__ etype, const int* __restrict__ dst,
                             int E, int R, int chunk,
                             int* __restrict__ blockHistT,   // [R][NB]
                             int* __restrict__ cnt)          // [N]
{
    __shared__ int lh[1024];
    for (int i = threadIdx.x; i < R; i += TPB) lh[i] = 0;
    __syncthreads();
    const int lo = blockIdx.x * chunk, hi = min(E, lo + chunk);
    for (int e = lo + threadIdx.x; e < hi; e += TPB) {
        atomicAdd(&lh[etype[e]], 1);
        atomicAdd(&cnt[dst[e]], 1);
    }
    __syncthreads();
    for (int r = threadIdx.x; r < R; r += TPB)
        blockHistT[r * NB + blockIdx.x] = lh[r];
}

// ---- S2: fused scan: blockHistT row scans + rel/task scan + dst scan -
__global__ __launch_bounds__(1024)
void scanF_kernel(int* __restrict__ blockHistT, int R, int E, int N,
                  int* __restrict__ rel_start,
                  int* __restrict__ task_rel, int* __restrict__ task_start,
                  int* __restrict__ n_tasks,
                  const int* __restrict__ cnt,
                  int* __restrict__ dst_base, int* __restrict__ cursor_dst)
{
    const int t = threadIdx.x;
    __shared__ int qsum[1024];
    __shared__ int sa[1024];
    __shared__ int sc[1024];
    __shared__ int sb[1024];

    // per-row quarter sums (4 threads per relation row; R <= 256)
    const int r = t >> 2, qt = t & 3;
    int qs = 0;
    if (r < R) {
        const int base = r * NB + qt * (NB / 4);
        for (int b = 0; b < NB / 4; ++b) qs += blockHistT[base + b];
    }
    qsum[t] = qs;
    __syncthreads();

    // in-row exclusive rewalk (quarter base from qsum; qsum is read-only now)
    if (r < R) {
        int acc = 0;
        for (int k = 0; k < qt; ++k) acc += qsum[(r << 2) + k];
        const int base = r * NB + qt * (NB / 4);
        for (int b = 0; b < NB / 4; ++b) {
            const int v = blockHistT[base + b];
            blockHistT[base + b] = acc;
            acc += v;
        }
    }

    // rel totals -> HS scan for rel_start + task bases (verified scanB form)
    const int tot = (t < R) ? (qsum[t << 2] + qsum[(t << 2) + 1] +
                               qsum[(t << 2) + 2] + qsum[(t << 2) + 3]) : 0;
    const int nb  = (tot + TPB - 1) / TPB;
    sa[t] = tot; sc[t] = nb;
    __syncthreads();
    for (int off = 1; off < 1024; off <<= 1) {
        const int va = (t >= off) ? sa[t - off] : 0;
        const int vc = (t >= off) ? sc[t - off] : 0;
        __syncthreads();
        sa[t] += va; sc[t] += vc;
        __syncthreads();
    }
    if (t < R) {
        const int st = sa[t] - tot;     // exclusive
        const int tb = sc[t] - nb;
        rel_start[t] = st;
        for (int b = 0; b < nb; ++b) {
            task_rel[tb + b]   = t;
            task_start[tb + b] = st + b * TPB;
        }
    }
    if (t == R - 1) {
        rel_start[R] = sa[t];
        *n_tasks = sc[t];
    }

    // dst exclusive scan over N bins (verified s2/scanB pattern)
    const int chunk = (N + 1023) >> 10;
    const int lo = t * chunk, hi = min(N, lo + chunk);
    int part = 0;
    for (int i = lo; i < hi; ++i) part += cnt[i];
    sb[t] = part;
    __syncthreads();
    for (int off = 1; off < 1024; off <<= 1) {
        const int v = (t >= off) ? sb[t - off] : 0;
        __syncthreads();
        sb[t] += v;
        __syncthreads();
    }
    int base2 = sb[t] - part;           // exclusive prefix of this chunk
    for (int i = lo; i < hi; ++i) {
        dst_base[i]   = base2;
        cursor_dst[i] = base2;
        base2 += cnt[i];
    }
    if (t == 0) dst_base[N] = E;
}

// ---- S3: scatter into rel order; record dst-order slot per edge ------
__global__ void scatter4_kernel(const int* __restrict__ src, const int* __restrict__ dst,
                                const int* __restrict__ etype, int E, int R, int chunk,
                                const int* __restrict__ blockHistT,
                                const int* __restrict__ rel_start,
                                int* __restrict__ cursor_dst,
                                int* __restrict__ ssrc, int* __restrict__ tpos)
{
    __shared__ int cur[1024];
    for (int r = threadIdx.x; r < R; r += TPB)
        cur[r] = rel_start[r] + blockHistT[r * NB + blockIdx.x];
    __syncthreads();
    const int lo = blockIdx.x * chunk, hi = min(E, lo + chunk);
    for (int e = lo + threadIdx.x; e < hi; e += TPB) {
        const int p = atomicAdd(&cur[etype[e]], 1);        // LDS cursor
        ssrc[p] = src[e];
        tpos[p] = atomicAdd(&cursor_dst[dst[e]], 1);       // dst-order slot (R2 form)
    }
}

// ---- MAIN: rel-task GEMV + relu + slot stats + dst-order msg stores --
__global__ __launch_bounds__(TPB)
void main4_kernel(const float* __restrict__ h, const float* __restrict__ W,
                  const int* __restrict__ rel_start,
                  const int* __restrict__ task_rel, const int* __restrict__ task_start,
                  const int* __restrict__ n_tasks_p,
                  const int* __restrict__ ssrc, const int* __restrict__ tpos,
                  float* __restrict__ msg,
                  float* __restrict__ stat_part)   // [NSLOT][2*D]
{
    __shared__ float s_tile[TPB * 33];
    __shared__ int   s_src[TPB];
    __shared__ int   s_tpos[TPB];
    __shared__ float s_aux[2 * TPB];

    const int task = blockIdx.x;
    if (task >= *n_tasks_p) return;
    const int r      = task_rel[task];
    const int start  = task_start[task];
    const int relEnd = rel_start[r + 1];
    const int nE     = min(TPB, relEnd - start);
    const int tid    = threadIdx.x;

    if (tid < nE) {
        s_src[tid]  = ssrc[start + tid];
        s_tpos[tid] = tpos[start + tid];
    }
    __syncthreads();

    for (int i = tid; i < nE * 8; i += TPB) {
        const int row = i >> 3, seg = i & 7;
        const float4 v = *(const float4*)(h + (size_t)s_src[row] * D + seg * 4);
        float* p = &s_tile[row * 33 + seg * 4];
        p[0] = v.x; p[1] = v.y; p[2] = v.z; p[3] = v.w;
    }
    __syncthreads();

    const float* Wr = W + (size_t)__builtin_amdgcn_readfirstlane(r) * (D * D);

    float acc[D];
#pragma unroll
    for (int o = 0; o < D; ++o) acc[o] = 0.f;

    if (tid < nE) {
#pragma unroll 4
        for (int d = 0; d < D; ++d) {
            const float hd = s_tile[tid * 33 + d];
#pragma unroll
            for (int o = 0; o < D; ++o)
                acc[o] = fmaf(hd, Wr[d * D + o], acc[o]);
        }
#pragma unroll
        for (int o = 0; o < D; ++o) acc[o] = fmaxf(acc[o], 0.f);
    }
    __syncthreads();

    if (tid < nE) {
#pragma unroll
        for (int o = 0; o < D; ++o) s_tile[tid * 33 + o] = acc[o];
    }
    __syncthreads();

    // dst-order stores: each row is one contiguous 128B line (R5-verified)
    float ps = 0.f, pq = 0.f;
    for (int i = tid; i < nE * D; i += TPB) {
        const int row = i >> 5, o = i & 31;   // o == tid&31: fixed dim per thread
        const float v = s_tile[row * 33 + o];
        msg[(size_t)s_tpos[row] * D + o] = v;
        ps += v; pq += v * v;
    }
    s_aux[tid]       = ps;
    s_aux[TPB + tid] = pq;
    __syncthreads();
    if (tid < D) {
        float ss = 0.f, sq = 0.f;
#pragma unroll
        for (int c = 0; c < TPB / D; ++c) {
            ss += s_aux[c * D + tid];
            sq += s_aux[TPB + c * D + tid];
        }
        float* sp = stat_part + (size_t)(blockIdx.x & (NSLOT - 1)) * (2 * D);
        atomicAdd(&sp[tid],     ss);
        atomicAdd(&sp[D + tid], sq);
    }
}

// ---- REDUCE: streaming contiguous segments + slot fold + BN + mean ---
__global__ __launch_bounds__(TPB)
void reduceS_kernel(const float* __restrict__ msg,
                    const int* __restrict__ dst_base,
                    const float* __restrict__ stat_part,
                    const float* __restrict__ gamma, const float* __restrict__ beta,
                    float invE, int N, float* __restrict__ out)
{
    __shared__ float s_sc[D], s_sh[D];
    const int tid = threadIdx.x;
    if (tid < D) {
        float ss = 0.f, qq = 0.f;
#pragma unroll 4
        for (int s = 0; s < NSLOT; ++s) {
            ss += stat_part[(size_t)s * (2 * D) + tid];
            qq += stat_part[(size_t)s * (2 * D) + D + tid];
        }
        const float mu  = ss * invE;
        const float var = fmaxf(qq * invE - mu * mu, 0.f);
        const float is  = rsqrtf(var + EPS);
        const float sc  = gamma[tid] * is;
        s_sc[tid] = sc;
        s_sh[tid] = fmaf(-mu, sc, beta[tid]);
    }
    __syncthreads();
    const int o    = tid & (D - 1);
    const int node = blockIdx.x * (TPB / D) + (tid >> 5);
    if (node >= N) return;
    const int b0 = dst_base[node], b1 = dst_base[node + 1];
    float v = 0.f;
    for (int q = b0; q < b1; ++q)
        v += msg[(size_t)q * D + o];               // contiguous streaming
    const float c = (float)(b1 - b0);
    out[(size_t)node * D + o] = fmaf(v, s_sc[o], s_sh[o] * c) / fmaxf(c, 1.0f);
}

// ======================================================================
// FALLBACK (original R0 path, verified) — used when guards fail
// ======================================================================

__global__ void hist2_kernel(const int* __restrict__ etype, int E, int R, int chunk,
                             int* __restrict__ blockHistT)
{
    __shared__ int lh[1024];
    for (int i = threadIdx.x; i < R; i += TPB) lh[i] = 0;
    __syncthreads();
    const int lo = blockIdx.x * chunk, hi = min(E, lo + chunk);
    for (int e = lo + threadIdx.x; e < hi; e += TPB)
        atomicAdd(&lh[etype[e]], 1);
    __syncthreads();
    for (int r = threadIdx.x; r < R; r += TPB)
        blockHistT[r * NB + blockIdx.x] = lh[r];
}

__global__ void scan2_kernel(int* __restrict__ blockHistT, int R,
                             int* __restrict__ rel_start,
                             int* __restrict__ task_rel, int* __restrict__ task_start,
                             int* __restrict__ n_tasks)
{
    __shared__ int tot[1024];
    __shared__ int s_start[1025];
    __shared__ int s_tbase[1024];
    const int r = threadIdx.x;
    if (r < R) {
        int acc = 0;
        int* p = blockHistT + r * NB;
        for (int b = 0; b < NB; ++b) { int v = p[b]; p[b] = acc; acc += v; }
        tot[r] = acc;
    }
    __syncthreads();
    if (threadIdx.x == 0) {
        int acc = 0, tb = 0;
        for (int rr = 0; rr < R; ++rr) {
            s_start[rr] = acc; s_tbase[rr] = tb;
            acc += tot[rr];
            tb  += (tot[rr] + TPB - 1) / TPB;
        }
        s_start[R] = acc;
        rel_start[R] = acc;
        *n_tasks = tb;
    }
    __syncthreads();
    if (r < R) {
        const int st = s_start[r];
        rel_start[r] = st;
        const int nb = (tot[r] + TPB - 1) / TPB;
        const int tb = s_tbase[r];
        for (int b = 0; b < nb; ++b) {
            task_rel[tb + b]   = r;
            task_start[tb + b] = st + b * TPB;
        }
    }
}

__global__ void scatter2_kernel(const int* __restrict__ src, const int* __restrict__ dst,
                                const int* __restrict__ etype, int E, int R, int chunk,
                                const int* __restrict__ blockHistT,
                                const int* __restrict__ rel_start,
                                int* __restrict__ ssrc, int* __restrict__ sdst)
{
    __shared__ int cur[1024];
    for (int r = threadIdx.x; r < R; r += TPB)
        cur[r] = rel_start[r] + blockHistT[r * NB + blockIdx.x];
    __syncthreads();
    const int lo = blockIdx.x * chunk, hi = min(E, lo + chunk);
    for (int e = lo + threadIdx.x; e < hi; e += TPB) {
        const int p = atomicAdd(&cur[etype[e]], 1);
        ssrc[p] = src[e];
        sdst[p] = dst[e];
    }
}

__global__ __launch_bounds__(TPB)
void rgcn_main(const float* __restrict__ h, const float* __restrict__ W,
               const int* __restrict__ rel_start,
               const int* __restrict__ task_rel, const int* __restrict__ task_start,
               const int* __restrict__ n_tasks_p,
               const int* __restrict__ ssrc, const int* __restrict__ sdst,
               float* __restrict__ out,
               float* __restrict__ stat_sum, float* __restrict__ stat_sq,
               float* __restrict__ cnt)
{
    __shared__ float s_tile[TPB * 33];
    __shared__ int   s_src[TPB];
    __shared__ int   s_dst[TPB];
    __shared__ float s_aux[2 * TPB];

    const int task = blockIdx.x;
    if (task >= *n_tasks_p) return;
    const int r      = task_rel[task];
    const int start  = task_start[task];
    const int relEnd = rel_start[r + 1];
    const int nE     = min(TPB, relEnd - start);
    const int tid    = threadIdx.x;

    if (tid < nE) {
        s_src[tid] = ssrc[start + tid];
        s_dst[tid] = sdst[start + tid];
    }
    __syncthreads();

    for (int i = tid; i < nE * 8; i += TPB) {
        const int row = i >> 3, seg = i & 7;
        const float4 v = *(const float4*)(h + (size_t)s_src[row] * D + seg * 4);
        float* p = &s_tile[row * 33 + seg * 4];
        p[0] = v.x; p[1] = v.y; p[2] = v.z; p[3] = v.w;
    }
    __syncthreads();

    const float* Wr = W + (size_t)__builtin_amdgcn_readfirstlane(r) * (D * D);

    float acc[D];
#pragma unroll
    for (int o = 0; o < D; ++o) acc[o] = 0.f;

    if (tid < nE) {
#pragma unroll 4
        for (int d = 0; d < D; ++d) {
            const float hd = s_tile[tid * 33 + d];
#pragma unroll
            for (int o = 0; o < D; ++o)
                acc[o] = fmaf(hd, Wr[d * D + o], acc[o]);
        }
#pragma unroll
        for (int o = 0; o < D; ++o) acc[o] = fmaxf(acc[o], 0.f);
        atomicAdd(&cnt[s_dst[tid]], 1.0f);
    }
    __syncthreads();

    if (tid < nE) {
#pragma unroll
        for (int o = 0; o < D; ++o) s_tile[tid * 33 + o] = acc[o];
    }
    __syncthreads();

    float ps = 0.f, pq = 0.f;
    for (int i = tid; i < nE * D; i += TPB) {
        const int row = i >> 5, o = i & 31;
        const float v = s_tile[row * 33 + o];
        atomicAdd(&out[(size_t)s_dst[row] * D + o], v);
        ps += v; pq += v * v;
    }
    s_aux[tid]       = ps;
    s_aux[TPB + tid] = pq;
    __syncthreads();
    if (tid < D) {
        float ss = 0.f, sq = 0.f;
#pragma unroll
        for (int c = 0; c < TPB / D; ++c) {
            ss += s_aux[c * D + tid];
            sq += s_aux[TPB + c * D + tid];
        }
        atomicAdd(&stat_sum[tid], ss);
        atomicAdd(&stat_sq[tid], sq);
    }
}

__global__ void finalize_kernel(float* __restrict__ out, const float* __restrict__ cnt,
                                const float* __restrict__ stat_sum,
                                const float* __restrict__ stat_sq,
                                const float* __restrict__ gamma,
                                const float* __restrict__ beta,
                                float invE, int total)
{
    const int i = blockIdx.x * TPB + threadIdx.x;
    if (i >= total) return;
    const int o    = i & 31;
    const int node = i >> 5;
    const float mu  = stat_sum[o] * invE;
    const float var = fmaxf(stat_sq[o] * invE - mu * mu, 0.f);
    const float is  = rsqrtf(var + EPS);
    const float sc  = gamma[o] * is;
    const float sh  = fmaf(-mu, sc, beta[o]);
    const float c   = cnt[node];
    out[i] = fmaf(out[i], sc, sh * c) / fmaxf(c, 1.0f);
}

// ======================================================================
extern "C" void kernel_launch(void* const* d_in, const int* in_sizes, int n_in,
                              void* d_out, int out_size, void* d_ws, size_t ws_size,
                              hipStream_t stream)
{
    const float* h     = (const float*)d_in[0];
    const float* W     = (const float*)d_in[1];
    const float* gamma = (const float*)d_in[2];
    const float* beta  = (const float*)d_in[3];
    const int*   src   = (const int*)d_in[4];
    const int*   dst   = (const int*)d_in[5];
    const int*   etype = (const int*)d_in[6];
    float* out = (float*)d_out;

    const int E = in_sizes[4];
    const int N = in_sizes[0] / D;
    const int R = in_sizes[1] / (D * D);
    const int T = R + (E + TPB - 1) / TPB;        // max task count
    const int chunk = (E + NB - 1) / NB;

    // ---------------- v8 workspace layout (dword offsets) ----------------
    const size_t o_statp      = 0;                           // [NSLOT][2*D]
    const size_t o_cnt        = o_statp + (size_t)NSLOT * 2 * D;
    const size_t zwords       = o_cnt + (size_t)N;           // zeroed prefix
    const size_t o_rel_start  = zwords;
    const size_t o_n_tasks    = o_rel_start + R + 1;
    const size_t o_task_rel   = o_n_tasks + 1;
    const size_t o_task_start = o_task_rel + T;
    const size_t o_blockHistT = o_task_start + T;
    const size_t o_dst_base   = o_blockHistT + (size_t)R * NB;
    const size_t o_cursor_dst = o_dst_base + N + 1;
    const size_t o_ssrc       = o_cursor_dst + N;
    const size_t o_tpos       = o_ssrc + (size_t)E;
    const size_t o_msg        = (o_tpos + (size_t)E + 3) & ~(size_t)3;  // 16B align
    const size_t total_words  = o_msg + (size_t)E * D;

    if (R >= 1 && R <= 256 && NB == TPB && ws_size >= total_words * 4) {
        // ------------------------- PATH v8 -------------------------------
        float* stat_part  = (float*)d_ws + o_statp;
        int*   cnt        = (int*)d_ws + o_cnt;
        int*   rel_start  = (int*)d_ws + o_rel_start;
        int*   n_tasks    = (int*)d_ws + o_n_tasks;
        int*   task_rel   = (int*)d_ws + o_task_rel;
        int*   task_start = (int*)d_ws + o_task_start;
        int*   blockHistT = (int*)d_ws + o_blockHistT;
        int*   dst_base   = (int*)d_ws + o_dst_base;
        int*   cursor_dst = (int*)d_ws + o_cursor_dst;
        int*   ssrc       = (int*)d_ws + o_ssrc;
        int*   tpos       = (int*)d_ws + o_tpos;
        float* msg        = (float*)d_ws + o_msg;

        hipMemsetAsync(d_ws, 0, zwords * 4, stream);

        hist3_kernel<<<NB, TPB, 0, stream>>>(etype, dst, E, R, chunk,
                                             blockHistT, cnt);
        scanF_kernel<<<1, 1024, 0, stream>>>(blockHistT, R, E, N,
                                             rel_start, task_rel, task_start,
                                             n_tasks, cnt, dst_base, cursor_dst);
        scatter4_kernel<<<NB, TPB, 0, stream>>>(src, dst, etype, E, R, chunk,
                                                blockHistT, rel_start,
                                                cursor_dst, ssrc, tpos);
        main4_kernel<<<T, TPB, 0, stream>>>(h, W, rel_start, task_rel, task_start,
                                            n_tasks, ssrc, tpos, msg, stat_part);
        reduceS_kernel<<<(N + TPB / D - 1) / (TPB / D), TPB, 0, stream>>>(
            msg, dst_base, stat_part, gamma, beta, 1.0f / (float)E, N, out);
        return;
    }

    // --------------------------- OLD PATH --------------------------------
    float* stat_sum  = (float*)d_ws;
    float* stat_sq   = stat_sum + D;
    float* cntf      = stat_sq + D;
    int*   rel_start = (int*)(cntf + N);
    int*   n_tasks   = rel_start + R + 1;
    int*   task_rel  = n_tasks + 1;
    int*   task_start= task_rel + T;
    int*   blockHistT= task_start + T;
    int*   ssrc      = blockHistT + R * NB;
    int*   sdst      = ssrc + E;

    hipMemsetAsync(d_ws, 0, sizeof(float) * (size_t)(2 * D + N), stream);
    hipMemsetAsync(d_out, 0, sizeof(float) * (size_t)out_size, stream);

    hist2_kernel<<<NB, TPB, 0, stream>>>(etype, E, R, chunk, blockHistT);
    scan2_kernel<<<1, TPB, 0, stream>>>(blockHistT, R, rel_start,
                                        task_rel, task_start, n_tasks);
    scatter2_kernel<<<NB, TPB, 0, stream>>>(src, dst, etype, E, R, chunk,
                                            blockHistT, rel_start, ssrc, sdst);
    rgcn_main<<<T, TPB, 0, stream>>>(h, W, rel_start, task_rel, task_start,
                                     n_tasks, ssrc, sdst, out,
                                     stat_sum, stat_sq, cntf);
    finalize_kernel<<<(N * D + TPB - 1) / TPB, TPB, 0, stream>>>(
        out, cntf, stat_sum, stat_sq, gamma, beta, 1.0f / (float)E, N * D);
}